// Round 4
// baseline (562.858 us; speedup 1.0000x reference)
//
#include <hip/hip_runtime.h>

#define B_  32
#define C1  1024
#define C2  256
#define T_  2048
#define EPSF 1e-5f

typedef __attribute__((ext_vector_type(8))) short bf16x8;
typedef __attribute__((ext_vector_type(4))) float f32x4;

static __device__ __forceinline__ unsigned short f2bf(float f) {
    union { float f; unsigned u; } v; v.f = f;
    unsigned r = v.u + 0x7fffu + ((v.u >> 16) & 1u);   // RNE
    return (unsigned short)(r >> 16);
}
// async global->LDS, 16 B per lane; lds dest = wave-uniform base + lane*16
static __device__ __forceinline__ void g2l16(const void* g, void* l) {
    __builtin_amdgcn_global_load_lds(
        (const __attribute__((address_space(1))) unsigned int*)g,
        (__attribute__((address_space(3))) unsigned int*)l, 16, 0, 0);
}

// ---- K1: LDS-free transpose+convert+stats: x[b][c][t] -> xT[b][t][c] bf16.
// Thread owns 4 consecutive c x 256 t (16-t chunks). Reads: 64 B/lane/row
// contiguous (dense HBM granules). Writes: lanes run along c -> each uint2
// store instruction covers a contiguous 2 KiB row of xT. No LDS, no barriers.
__global__ __launch_bounds__(256) void k_prep(const float* __restrict__ x,
        unsigned short* __restrict__ xT, float* __restrict__ psum, float* __restrict__ psq) {
    int tid = threadIdx.x;
    int ts = blockIdx.x, b = blockIdx.y;
    int c0 = tid * 4;
    const float* xb = x + (size_t)b * C1 * T_;
    float s0=0,s1=0,s2=0,s3=0,q0=0,q1=0,q2=0,q3=0;
    for (int i = 0; i < 16; ++i) {
        int t0 = ts * 256 + i * 16;
        float a0[16], a1[16], a2[16], a3[16];
        #pragma unroll
        for (int j = 0; j < 4; ++j) {
            *(float4*)&a0[j*4] = *(const float4*)(xb + (size_t)(c0+0)*T_ + t0 + j*4);
            *(float4*)&a1[j*4] = *(const float4*)(xb + (size_t)(c0+1)*T_ + t0 + j*4);
            *(float4*)&a2[j*4] = *(const float4*)(xb + (size_t)(c0+2)*T_ + t0 + j*4);
            *(float4*)&a3[j*4] = *(const float4*)(xb + (size_t)(c0+3)*T_ + t0 + j*4);
        }
        #pragma unroll
        for (int tt = 0; tt < 16; ++tt) {
            float v0 = a0[tt], v1 = a1[tt], v2 = a2[tt], v3 = a3[tt];
            s0 += v0; q0 += v0*v0;  s1 += v1; q1 += v1*v1;
            s2 += v2; q2 += v2*v2;  s3 += v3; q3 += v3*v3;
            uint2 pk;
            pk.x = (unsigned)f2bf(v0) | ((unsigned)f2bf(v1) << 16);
            pk.y = (unsigned)f2bf(v2) | ((unsigned)f2bf(v3) << 16);
            *(uint2*)&xT[((size_t)b * T_ + t0 + tt) * C1 + c0] = pk;
        }
    }
    int prow = b * 8 + ts;          // 256 partial rows
    *(float4*)&psum[(size_t)prow * C1 + c0] = make_float4(s0, s1, s2, s3);
    *(float4*)&psq [(size_t)prow * C1 + c0] = make_float4(q0, q1, q2, q3);
}

// ---- K2: reduce partials -> scale1/shift1 (grid 4 x 256)
__global__ void k_scales1(const float* __restrict__ psum, const float* __restrict__ psq,
        const float* __restrict__ g, const float* __restrict__ bb,
        float* __restrict__ scale, float* __restrict__ shift) {
    int c = blockIdx.x * 256 + threadIdx.x;
    float s = 0.f, sq = 0.f;
    for (int r = 0; r < 256; ++r) { s += psum[(size_t)r * C1 + c]; sq += psq[(size_t)r * C1 + c]; }
    float n = (float)(B_ * T_);
    float mean = s / n;
    float var  = sq / n - mean * mean;
    float sc   = g[c] * rsqrtf(var + EPSF);
    scale[c] = sc;
    shift[c] = bb[c] - mean * sc;
}

// ---- K3: fold BN1 into w1 -> w1e bf16, b1e
__global__ void k_fold1(const float* __restrict__ w1, const float* __restrict__ b1,
                        const float* __restrict__ scale1, const float* __restrict__ shift1,
                        unsigned short* __restrict__ w1e, float* __restrict__ b1e) {
    int o = blockIdx.x, tid = threadIdx.x;
    float4 w = ((const float4*)(w1 + (size_t)o * C1))[tid];
    int c = tid * 4;
    float p = w.x * shift1[c] + w.y * shift1[c + 1] + w.z * shift1[c + 2] + w.w * shift1[c + 3];
    uint2 pk;
    pk.x = (unsigned)f2bf(w.x * scale1[c])     | ((unsigned)f2bf(w.y * scale1[c + 1]) << 16);
    pk.y = (unsigned)f2bf(w.z * scale1[c + 2]) | ((unsigned)f2bf(w.w * scale1[c + 3]) << 16);
    *((uint2*)(w1e + (size_t)o * C1 + c)) = pk;
    __shared__ float rs[256];
    rs[tid] = p; __syncthreads();
    for (int off = 128; off > 0; off >>= 1) {
        if (tid < off) rs[tid] += rs[tid + off];
        __syncthreads();
    }
    if (tid == 0) b1e[o] = b1[o] + rs[0];
}

// ---- K4: GEMM1 256(o)x128(t), K=1024, BK=32. xT read ONCE per element.
// Epilogue: bias+relu -> hT bf16, plus per-block h-stats partials.
__global__ __launch_bounds__(256, 2) void k_gemm1(const unsigned short* __restrict__ xT,
        const unsigned short* __restrict__ w1e, const float* __restrict__ b1e,
        unsigned short* __restrict__ hT, float* __restrict__ p2s, float* __restrict__ p2q) {
    __shared__ unsigned short sA[256 * 32];   // 16 KiB  w1e tile [o][k]
    __shared__ unsigned short sB[128 * 32];   //  8 KiB  xT tile [t][k]
    int bn = blockIdx.x, b = blockIdx.y;
    int tid = threadIdx.x;
    int wave = tid >> 6, lane = tid & 63;
    int wm = wave >> 1, wn = wave & 1;        // wave: 128(o) x 64(t)
    int l15 = lane & 15, q = lane >> 4;
    f32x4 acc[8][4] = {};
    const unsigned short* xblk = xT + ((size_t)b * T_ + (size_t)bn * 128) * C1;

    for (int k0 = 0; k0 < C1; k0 += 32) {
        #pragma unroll
        for (int i = 0; i < 4; ++i) {         // A: 16 segments of 1 KiB
            int idx = (wave * 4 + i) * 64 + lane;
            int row = idx >> 2, cq = idx & 3;
            g2l16(w1e + (size_t)row * C1 + k0 + cq * 8, &sA[(wave * 4 + i) * 512]);
        }
        #pragma unroll
        for (int i = 0; i < 2; ++i) {         // B: 8 segments
            int idx = (wave * 2 + i) * 64 + lane;
            int row = idx >> 2, cq = idx & 3;
            g2l16(xblk + (size_t)row * C1 + k0 + cq * 8, &sB[(wave * 2 + i) * 512]);
        }
        __syncthreads();
        bf16x8 bfr[4];
        #pragma unroll
        for (int ni = 0; ni < 4; ++ni)
            bfr[ni] = *((const bf16x8*)&sB[(wn * 64 + ni * 16 + l15) * 32 + q * 8]);
        #pragma unroll
        for (int mi = 0; mi < 8; ++mi) {
            bf16x8 af = *((const bf16x8*)&sA[(wm * 128 + mi * 16 + l15) * 32 + q * 8]);
            #pragma unroll
            for (int ni = 0; ni < 4; ++ni)
                acc[mi][ni] = __builtin_amdgcn_mfma_f32_16x16x32_bf16(af, bfr[ni], acc[mi][ni], 0, 0, 0);
        }
        __syncthreads();
    }
    // epilogue. C/D: col(t)=l15, row(o)=q*4+reg
    int obase = wm * 128;
    int tbase = bn * 128 + wn * 64;
    int prow = (b * 16 + bn) * 2 + wn;        // 1024 partial rows
    #pragma unroll
    for (int mi = 0; mi < 8; ++mi) {
        int og = obase + mi * 16 + q * 4;
        float4 bias = *(const float4*)&b1e[og];
        float s0 = 0, s1 = 0, s2 = 0, s3 = 0, q0 = 0, q1 = 0, q2 = 0, q3 = 0;
        #pragma unroll
        for (int ni = 0; ni < 4; ++ni) {
            int t = tbase + ni * 16 + l15;
            float v0 = fmaxf(acc[mi][ni][0] + bias.x, 0.f);
            float v1 = fmaxf(acc[mi][ni][1] + bias.y, 0.f);
            float v2 = fmaxf(acc[mi][ni][2] + bias.z, 0.f);
            float v3 = fmaxf(acc[mi][ni][3] + bias.w, 0.f);
            s0 += v0; q0 += v0 * v0;  s1 += v1; q1 += v1 * v1;
            s2 += v2; q2 += v2 * v2;  s3 += v3; q3 += v3 * v3;
            uint2 pk;
            pk.x = (unsigned)f2bf(v0) | ((unsigned)f2bf(v1) << 16);
            pk.y = (unsigned)f2bf(v2) | ((unsigned)f2bf(v3) << 16);
            *(uint2*)&hT[((size_t)b * T_ + t) * C2 + og] = pk;
        }
        #pragma unroll
        for (int m = 1; m <= 8; m <<= 1) {    // butterfly over l15 (16-lane groups)
            s0 += __shfl_xor(s0, m); s1 += __shfl_xor(s1, m);
            s2 += __shfl_xor(s2, m); s3 += __shfl_xor(s3, m);
            q0 += __shfl_xor(q0, m); q1 += __shfl_xor(q1, m);
            q2 += __shfl_xor(q2, m); q3 += __shfl_xor(q3, m);
        }
        if (l15 == 0) {
            *(float4*)&p2s[(size_t)prow * C2 + og] = make_float4(s0, s1, s2, s3);
            *(float4*)&p2q[(size_t)prow * C2 + og] = make_float4(q0, q1, q2, q3);
        }
    }
}

// ---- K5: fused scales2+fold2: 64 blocks (one per o); thread = channel c
__global__ __launch_bounds__(256) void k_fold2(const float* __restrict__ w2,
        const float* __restrict__ b2, const float* __restrict__ g2, const float* __restrict__ bb2,
        const float* __restrict__ p2s, const float* __restrict__ p2q,
        unsigned short* __restrict__ w2e, float* __restrict__ b2e) {
    int o = blockIdx.x, tid = threadIdx.x;   // tid == c
    float s = 0.f, sq = 0.f;
    for (int r = 0; r < 1024; ++r) {
        s  += p2s[(size_t)r * C2 + tid];
        sq += p2q[(size_t)r * C2 + tid];
    }
    const float n = (float)(B_ * T_);
    float mean = s / n;
    float sc = g2[tid] * rsqrtf(sq / n - mean * mean + EPSF);
    float sh = bb2[tid] - mean * sc;
    float w = w2[(size_t)o * C2 + tid];
    float p = w * sh;
    w2e[(size_t)o * C2 + tid] = f2bf(w * sc);
    __shared__ float rs[256];
    rs[tid] = p; __syncthreads();
    for (int off = 128; off > 0; off >>= 1) {
        if (tid < off) rs[tid] += rs[tid + off];
        __syncthreads();
    }
    if (tid == 0) b2e[o] = b2[o] + rs[0];
}

// ---- K6: GEMM2: out = w2e @ hT + b2e, split mu/logvar. 64(o) x 128(t), K=256.
__global__ __launch_bounds__(256) void k_gemm2(const unsigned short* __restrict__ hT,
        const unsigned short* __restrict__ w2e, const float* __restrict__ b2e,
        float* __restrict__ out) {
    __shared__ unsigned short sA[64 * 32];    // 4 KiB
    __shared__ unsigned short sB[128 * 32];   // 8 KiB
    int bn = blockIdx.x, b = blockIdx.y;
    int tid = threadIdx.x;
    int wave = tid >> 6, lane = tid & 63;
    int l15 = lane & 15, q = lane >> 4;
    f32x4 acc[4][2] = {};
    const unsigned short* hblk = hT + ((size_t)b * T_ + (size_t)bn * 128) * C2;

    for (int k0 = 0; k0 < C2; k0 += 32) {
        {                                      // A: 4 segments, one per wave
            int idx = wave * 64 + lane;
            int row = idx >> 2, cq = idx & 3;
            g2l16(w2e + (size_t)row * C2 + k0 + cq * 8, &sA[wave * 512]);
        }
        #pragma unroll
        for (int i = 0; i < 2; ++i) {          // B: 8 segments
            int idx = (wave * 2 + i) * 64 + lane;
            int row = idx >> 2, cq = idx & 3;
            g2l16(hblk + (size_t)row * C2 + k0 + cq * 8, &sB[(wave * 2 + i) * 512]);
        }
        __syncthreads();
        bf16x8 af[4], bfr[2];
        #pragma unroll
        for (int mi = 0; mi < 4; ++mi)
            af[mi] = *((const bf16x8*)&sA[(mi * 16 + l15) * 32 + q * 8]);
        #pragma unroll
        for (int ni = 0; ni < 2; ++ni)
            bfr[ni] = *((const bf16x8*)&sB[(wave * 32 + ni * 16 + l15) * 32 + q * 8]);
        #pragma unroll
        for (int mi = 0; mi < 4; ++mi)
            #pragma unroll
            for (int ni = 0; ni < 2; ++ni)
                acc[mi][ni] = __builtin_amdgcn_mfma_f32_16x16x32_bf16(af[mi], bfr[ni], acc[mi][ni], 0, 0, 0);
        __syncthreads();
    }
    int tbase = bn * 128 + wave * 32;
    #pragma unroll
    for (int mi = 0; mi < 4; ++mi) {
        #pragma unroll
        for (int reg = 0; reg < 4; ++reg) {
            int o = mi * 16 + q * 4 + reg;
            float bias = b2e[o];
            size_t base = (o < 32)
                ? ((size_t)b * 32 * T_ + (size_t)o * T_)
                : (2097152u + (size_t)b * 32 * T_ + (size_t)(o - 32) * T_);
            #pragma unroll
            for (int ni = 0; ni < 2; ++ni) {
                int t = tbase + ni * 16 + l15;
                out[base + t] = acc[mi][ni][reg] + bias;
            }
        }
    }
}

extern "C" void kernel_launch(void* const* d_in, const int* in_sizes, int n_in,
                              void* d_out, int out_size, void* d_ws, size_t ws_size,
                              hipStream_t stream) {
    const float* x   = (const float*)d_in[0];
    const float* g1  = (const float*)d_in[1];
    const float* bb1 = (const float*)d_in[2];
    const float* w1  = (const float*)d_in[3];
    const float* b1  = (const float*)d_in[4];
    const float* g2  = (const float*)d_in[5];
    const float* bb2 = (const float*)d_in[6];
    const float* w2  = (const float*)d_in[7];
    const float* b2  = (const float*)d_in[8];
    float* out = (float*)d_out;

    char* ws = (char*)d_ws;
    float* b1e    = (float*)(ws + 0);                     //   4 KiB
    float* b2e    = (float*)(ws + 4096);                  //   1 KiB
    float* scale1 = (float*)(ws + 8192);                  //   4 KiB
    float* shift1 = (float*)(ws + 12288);                 //   4 KiB
    float* psum   = (float*)(ws + 16384);                 //   1 MiB  [256][1024]
    float* psq    = (float*)(ws + 1064960);               //   1 MiB
    float* p2s    = (float*)(ws + 2113536);               //   1 MiB  [1024][256]
    float* p2q    = (float*)(ws + 3162112);               //   1 MiB
    unsigned short* w1e = (unsigned short*)(ws + 4210688);    // 512 KiB
    unsigned short* w2e = (unsigned short*)(ws + 4734976);    //  32 KiB
    unsigned short* xT  = (unsigned short*)(ws + 4767744);    // 128 MiB [b][t][c1]
    unsigned short* hT  = (unsigned short*)(ws + 4767744 + 134217728); // 32 MiB [b][t][c2]

    k_prep   <<<dim3(8, 32),  dim3(256), 0, stream>>>(x, xT, psum, psq);
    k_scales1<<<dim3(4),      dim3(256), 0, stream>>>(psum, psq, g1, bb1, scale1, shift1);
    k_fold1  <<<dim3(256),    dim3(256), 0, stream>>>(w1, b1, scale1, shift1, w1e, b1e);
    k_gemm1  <<<dim3(16, 32), dim3(256), 0, stream>>>(xT, w1e, b1e, hT, p2s, p2q);
    k_fold2  <<<dim3(64),     dim3(256), 0, stream>>>(w2, b2, g2, bb2, p2s, p2q, w2e, b2e);
    k_gemm2  <<<dim3(16, 32), dim3(256), 0, stream>>>(hT, w2e, b2e, out);
}